// Round 6
// baseline (576.528 us; speedup 1.0000x reference)
//
#include <hip/hip_runtime.h>
#include <stdint.h>

namespace {

constexpr int DIM  = 180;     // channels = H*DH
constexpr int LL   = 14336;
constexpr int B    = 16;
constexpr int T    = 28;      // tokens per block (4 windows)
constexpr int NCH  = 512;     // chunks per batch
constexpr int EQKV = 540;
constexpr int EPAD = 192;     // padded K / per-part channel span

constexpr int QT_STRIDE = 584;  // u16 per token row: 3*192 + 8 pad (1168 B)

typedef __attribute__((ext_vector_type(8))) short bf16x8;
typedef __attribute__((ext_vector_type(4))) float f32x4;

union Frag { bf16x8 v; uint32_t u[4]; unsigned short s[8]; };

__device__ __forceinline__ unsigned short f2b(float f) {
  uint32_t u = __builtin_bit_cast(uint32_t, f);
  u = (u + 0x7fffu + ((u >> 16) & 1u)) >> 16;   // RNE
  return (unsigned short)u;
}
__device__ __forceinline__ uint32_t pack2(float lo, float hi) {
  return (uint32_t)f2b(lo) | ((uint32_t)f2b(hi) << 16);
}
__device__ __forceinline__ float blo(uint32_t u) { return __builtin_bit_cast(float, u << 16); }
__device__ __forceinline__ float bhi(uint32_t u) { return __builtin_bit_cast(float, u & 0xffff0000u); }
__device__ __forceinline__ f32x4 zero4() { f32x4 z = {0.f,0.f,0.f,0.f}; return z; }
__device__ __forceinline__ bf16x8 zfrag() {
  Frag f; f.u[0]=f.u[1]=f.u[2]=f.u[3]=0u; return f.v;
}

} // namespace

// ---- prep: fp32 weights -> bf16, K-padded / head-padded layouts in ws ----
__global__ __launch_bounds__(1024) void la_prep(
    const float* __restrict__ Wq, const float* __restrict__ Wkv,
    const float* __restrict__ Wo, unsigned short* __restrict__ wqkv_b,
    unsigned short* __restrict__ wo_b) {
  const int idx = (int)(blockIdx.x * 1024 + threadIdx.x);
  if (idx < EQKV * EPAD) {
    const int e = idx / EPAD, c = idx - e * EPAD;
    float v = 0.f;
    if (c < DIM) v = (e < DIM) ? Wq[e * DIM + c] : Wkv[(size_t)(e - DIM) * DIM + c];
    wqkv_b[idx] = f2b(v);
  } else {
    const int k = idx - EQKV * EPAD;
    if (k < DIM * EPAD) {
      const int o = k / EPAD, cc = k - o * EPAD;
      const int h = cc >> 5, d = cc & 31;
      float v = 0.f;
      if (d < 30) v = Wo[o * DIM + h * 30 + d];
      wo_b[k] = f2b(v);
    }
  }
}

// ---- fused main: 512 threads (8 waves), T=28 tokens, 3-4 blocks/CU ----
__global__ __launch_bounds__(512, 6) void la_main(
    const float* __restrict__ fmap, const unsigned short* __restrict__ wqkv,
    const unsigned short* __restrict__ wo_b, const float* __restrict__ bo,
    float* __restrict__ out) {
  __shared__ __align__(16) unsigned short qt[T * QT_STRIDE];  // 32,704 B

  const int tid  = (int)threadIdx.x;
  const int wave = tid >> 6;
  const int lane = tid & 63;
  const int l15  = lane & 15;
  const int g    = lane >> 4;

  const int bi    = (int)blockIdx.x;
  const int b     = bi >> 9;
  const int chunk = bi & 511;
  const int t0    = chunk * T;

  // ============ stage 1: qkv = Wqkv @ x -> qt[t][part*192+h*32+d] ===========
  // wave = (m-quarter mq: 9 m-tiles) x (n-half: tokens n*16..)
  const int mq = wave >> 1;
  const int n  = wave & 1;
  const int tl = n * 16 + l15;          // block-local token this lane owns (B)
  const bool tvalid = (tl < T);

  // x B-fragments straight from global into registers (once per block)
  Frag breg[6];
  {
    const float* xbase = fmap + (size_t)b * DIM * LL + t0 + tl;
#pragma unroll
    for (int ks = 0; ks < 6; ++ks) {
#pragma unroll
      for (int j = 0; j < 8; ++j) {
        const int c = ks * 32 + g * 8 + j;
        float v = 0.f;
        if (tvalid && c < DIM) v = xbase[c * LL];
        breg[ks].s[j] = f2b(v);
      }
    }
  }

#pragma unroll 3
  for (int k9 = 0; k9 < 9; ++k9) {
    const int mt  = mq * 9 + k9;
    const int e_a = mt * 16 + l15;
    f32x4 acc = zero4();
#pragma unroll
    for (int ks = 0; ks < 6; ++ks) {
      const bf16x8 a = (e_a < EQKV)
          ? *(const bf16x8*)(wqkv + (size_t)e_a * EPAD + ks * 32 + g * 8)
          : zfrag();
      acc = __builtin_amdgcn_mfma_f32_16x16x32_bf16(a, breg[ks].v, acc, 0, 0, 0);
    }
    // writeback: C layout col=t=lane&15, row=e=(lane>>4)*4+r
    if (tvalid) {
      unsigned short* qrow = qt + tl * QT_STRIDE;
      const int e0 = mt * 16 + g * 4;
#pragma unroll
      for (int r = 0; r < 4; ++r) {
        const int e = e0 + r;
        if (e < EQKV) {
          const int part = (e >= 360) ? 2 : ((e >= DIM) ? 1 : 0);
          const int rr = e - part * DIM;
          const int h  = (rr * 34953) >> 20;   // rr/30 for rr<1916
          const int d  = rr - h * 30;
          qrow[part * EPAD + h * 32 + d] = f2b(acc[r]);
        }
      }
    }
  }
  __syncthreads();

  // ============ stage 2: windowed softmax-attention (4 windows) =============
  if (tid < 168) {  // (w,h,i): 4*6*7
    const float scale = 0.18257418583505536f;  // 30^-0.5
    const int w   = tid / 42;
    const int rem = tid - w * 42;
    const int h   = rem / 7;
    const int i   = rem - h * 7;
    const int ti  = w * 7 + i;
    const uint32_t* qrow = (const uint32_t*)(qt + ti * QT_STRIDE + h * 32);
    const unsigned short* kbase = qt + (w * 7) * QT_STRIDE + EPAD + h * 32;
    float dots[7];
#pragma unroll
    for (int j = 0; j < 7; ++j) dots[j] = 0.f;
#pragma unroll
    for (int dp = 0; dp < 15; ++dp) {
      const uint32_t qu = qrow[dp];
      const float q0 = blo(qu), q1 = bhi(qu);
#pragma unroll
      for (int j = 0; j < 7; ++j) {
        const uint32_t ku = *(const uint32_t*)(kbase + j * QT_STRIDE + dp * 2);
        dots[j] += q0 * blo(ku);
        dots[j] += q1 * bhi(ku);
      }
    }
    float mx = dots[0];
#pragma unroll
    for (int j = 1; j < 7; ++j) mx = fmaxf(mx, dots[j]);
    float aw[7];
    float s = 0.f;
#pragma unroll
    for (int j = 0; j < 7; ++j) {
      const float pj = __expf(scale * (dots[j] - mx));
      aw[j] = pj; s += pj;
    }
    const float inv = 1.f / s;
#pragma unroll
    for (int j = 0; j < 7; ++j) aw[j] *= inv;
    const unsigned short* vbase = qt + (w * 7) * QT_STRIDE + 2 * EPAD + h * 32;
    uint32_t* orow = (uint32_t*)(qt + ti * QT_STRIDE + h * 32);
#pragma unroll
    for (int dp = 0; dp < 15; ++dp) {
      float o0 = 0.f, o1 = 0.f;
#pragma unroll
      for (int j = 0; j < 7; ++j) {
        const uint32_t vu = *(const uint32_t*)(vbase + j * QT_STRIDE + dp * 2);
        o0 += aw[j] * blo(vu);
        o1 += aw[j] * bhi(vu);
      }
      orow[dp] = pack2(o0, o1);
    }
    orow[15] = 0u;  // zero head-pad d=30,31 (K-padding for stage 3)
  }
  __syncthreads();

  // ============ stage 3: y = Wo @ att_out + bo ==============================
  for (int p = wave; p < 24; p += 8) {  // 12 m-tiles x 2 n-tiles
    const int m  = p >> 1;
    const int n3 = p & 1;
    const int o_a  = m * 16 + l15;
    const int tcol = n3 * 16 + l15;
    const int trd  = (tcol < T) ? tcol : (T - 1);  // clamp: read valid row,
    f32x4 acc = zero4();                           // result discarded below
#pragma unroll
    for (int ks = 0; ks < 6; ++ks) {
      const int c0 = ks * 32 + g * 8;
      const bf16x8 a = (o_a < DIM)
          ? *(const bf16x8*)(wo_b + (size_t)o_a * EPAD + c0) : zfrag();
      const bf16x8 bf = *(const bf16x8*)(qt + trd * QT_STRIDE + c0);
      acc = __builtin_amdgcn_mfma_f32_16x16x32_bf16(a, bf, acc, 0, 0, 0);
    }
    if (tcol < T) {
#pragma unroll
      for (int r = 0; r < 4; ++r) {
        const int o = m * 16 + g * 4 + r;
        if (o < DIM)
          out[(size_t)(b * DIM + o) * LL + t0 + tcol] = acc[r] + bo[o];
      }
    }
  }
}

extern "C" void kernel_launch(void* const* d_in, const int* in_sizes, int n_in,
                              void* d_out, int out_size, void* d_ws, size_t ws_size,
                              hipStream_t stream) {
  const float* fmap = (const float*)d_in[0];
  const float* Wq   = (const float*)d_in[1];
  const float* Wkv  = (const float*)d_in[2];
  const float* Wo   = (const float*)d_in[3];
  const float* bo   = (const float*)d_in[4];
  float* o = (float*)d_out;

  unsigned short* wqkv_b = (unsigned short*)d_ws;                  // 540*192 bf16
  unsigned short* wo_b   = wqkv_b + EQKV * EPAD;                   // 180*192 bf16

  const int prep_elems = EQKV * EPAD + DIM * EPAD;                 // 138,240
  hipLaunchKernelGGL(la_prep, dim3((prep_elems + 1023) / 1024), dim3(1024), 0,
                     stream, Wq, Wkv, Wo, wqkv_b, wo_b);
  hipLaunchKernelGGL(la_main, dim3(B * NCH), dim3(512), 0, stream,
                     fmap, wqkv_b, wo_b, bo, o);
}